// Round 2
// baseline (256.628 us; speedup 1.0000x reference)
//
#include <hip/hip_runtime.h>

// MHA forward: B=4, S=2048, D=1024, H=16, hd=64, causal+pad mask, scale=8.
// IO fp32; internal bf16 MFMA with fp32 accumulate.
// v14 = attention/prep unchanged (v12 bodies); GEMMs rebuilt on the PROVEN
// 256^2 8-phase template geometry: BM=BN=256, BK=64, 8 waves (2Mx4N),
// per-wave 128x64 output (acc[8][4]), 4 phases/K-tile of 16 MFMA each,
// LDS 128 KiB as a 2-parity half-tile slot ring, one half-tile stage per
// phase, counted vmcnt(4) once per K-tile (never drain in steady state),
// setprio(1) around each MFMA cluster, sched_barrier pinning.
// Stage ring during tile T: [T+1.B0, T+1.B1, T+2.A0, T+2.A1] — A slots die
// at ph1 (quadrant order (0,0),(1,0),(0,1),(1,1)), B stages hit the
// opposite-parity buffer. vmcnt(4) at tile end => tile T+1 fully resident.
// QKV grid 32x12=384 (%8==0), out-proj 32x4=128 (%8==0), bijective XCD remap.

typedef __attribute__((ext_vector_type(8))) short bf16x8;
typedef __attribute__((ext_vector_type(8))) unsigned short u16x8;
typedef __attribute__((ext_vector_type(4))) unsigned short u16x4;
typedef __attribute__((ext_vector_type(4))) float f32x4;

#define MFMA16 __builtin_amdgcn_mfma_f32_16x16x32_bf16

#define GLDS(gp, lp) __builtin_amdgcn_global_load_lds( \
    (const __attribute__((address_space(1))) unsigned int*)(gp), \
    (__attribute__((address_space(3))) unsigned int*)(lp), 16, 0, 0)

// phase gate: pin loads above, barrier, wait LDS, pin MFMA below, boost prio
#define PH_GATE() do { \
    __builtin_amdgcn_sched_barrier(0); \
    __builtin_amdgcn_s_barrier(); \
    asm volatile("s_waitcnt lgkmcnt(0)" ::: "memory"); \
    __builtin_amdgcn_sched_barrier(0); \
    __builtin_amdgcn_s_setprio(1); \
} while (0)

#define PH_END() do { \
    __builtin_amdgcn_s_setprio(0); \
    __builtin_amdgcn_sched_barrier(0); \
    __builtin_amdgcn_s_barrier(); \
} while (0)

__device__ __forceinline__ unsigned short f2bf(float f) {
    union { float f; unsigned int u; } v; v.f = f;
    unsigned int r = v.u + 0x7fffu + ((v.u >> 16) & 1u);
    return (unsigned short)(r >> 16);
}

// bx<4096: fp32->bf16 x-convert (+mask->bf16 in first 32 blocks).
// bx>=4096: weight transposes (w_qkv 1024x3072, w_out 1024x1024).
__global__ void k_prep(const float* __restrict__ x, unsigned short* __restrict__ xb,
                       const int* __restrict__ mask, unsigned short* __restrict__ mb,
                       const float* __restrict__ wqkv, unsigned short* __restrict__ w1t,
                       const float* __restrict__ wout, unsigned short* __restrict__ w2t) {
    __shared__ float tile[32][33];
    const int bx = blockIdx.x;
    if (bx < 4096) {
        size_t i = ((size_t)bx * 256 + threadIdx.x) * 8;
        float4 f0 = *(const float4*)(x + i);
        float4 f1 = *(const float4*)(x + i + 4);
        u16x8 v;
        v[0] = f2bf(f0.x); v[1] = f2bf(f0.y); v[2] = f2bf(f0.z); v[3] = f2bf(f0.w);
        v[4] = f2bf(f1.x); v[5] = f2bf(f1.y); v[6] = f2bf(f1.z); v[7] = f2bf(f1.w);
        *(u16x8*)(xb + i) = v;
        if (bx < 32) {
            int j = bx * 256 + threadIdx.x;
            mb[j] = mask[j] ? (unsigned short)0x3F80 : (unsigned short)0;
        }
    } else {
        const int b2 = bx - 4096;
        const int cb = b2 & 127, rb = b2 >> 7;
        const float* in = (cb < 96) ? wqkv : wout;
        unsigned short* out = (cb < 96) ? w1t : w2t;
        const int C = (cb < 96) ? 3072 : 1024;
        const int c0 = ((cb < 96) ? cb : cb - 96) * 32;
        const int r0 = rb * 32;
        int tx = threadIdx.x & 31, ty = threadIdx.x >> 5;
        for (int i = ty; i < 32; i += 8)
            tile[i][tx] = in[(size_t)(r0 + i) * C + (c0 + tx)];
        __syncthreads();
        for (int i = ty; i < 32; i += 8)
            out[(size_t)(c0 + i) * 1024 + (r0 + tx)] = f2bf(tile[tx][i]);
    }
}

// C[M][N] = A[M][K] * Bt[N][K]^T.  256x256 tile, BK=64, 8 waves 2Mx4N,
// per-wave 128x64, 4 phases of 16 MFMA per K-tile. NBX = gridDim.x.
template <int MODE, int NBX>
__global__ __launch_bounds__(512, 2) void k_gemm256(
    const unsigned short* __restrict__ Ab,
    const unsigned short* __restrict__ Bt,
    float* __restrict__ Cf,
    unsigned short* __restrict__ qb,
    unsigned short* __restrict__ kb,
    unsigned short* __restrict__ vt,
    const int* __restrict__ mask,
    int N, int K)
{
    __shared__ __align__(16) unsigned short la[2][256 * 64];   // 64 KB
    __shared__ __align__(16) unsigned short lb[2][256 * 64];   // 64 KB
    const int t = threadIdx.x;
    const int w = t >> 6, lane = t & 63;
    const int lr = lane & 15, lq = lane >> 4;
    const int lr7 = lr & 7;
    const int rowb = lane >> 3, c8 = lane & 7;
    const int g8 = ((c8 - rowb) & 7) * 8;     // rotation pre-swizzle (proven, 0 conflicts)

    // Bijective XCD chunk remap (grid sizes 384 and 128, both % 8 == 0).
    const int nwg = NBX * 32;
    const int orig = blockIdx.y * NBX + blockIdx.x;
    const int rm = (orig & 7) * (nwg >> 3) + (orig >> 3);
    const int m0 = (rm / NBX) * 256;
    const int n0 = (rm % NBX) * 256;

    const int wr = w >> 2;            // 0,1   M-half of wave
    const int wc = w & 3;             // 0..3  N-quarter of wave
    const int wm = wr * 128;
    const int wn = wc * 64;

    // stage one half-tile (128 rows x 64 cols) = 2 block-wide gload_lds
    auto stageA = [&](int tt2, int hf) {
        unsigned short* dst = &la[tt2 & 1][(hf * 128 + w * 8) * 64];
        const unsigned short* src =
            Ab + (size_t)(m0 + hf * 128 + w * 8 + rowb) * K + (size_t)tt2 * 64 + g8;
        GLDS(src, dst);
        GLDS(src + (size_t)64 * K, dst + 64 * 64);
    };
    auto stageB = [&](int tt2, int hf) {
        unsigned short* dst = &lb[tt2 & 1][(hf * 128 + w * 8) * 64];
        const unsigned short* src =
            Bt + (size_t)(n0 + hf * 128 + w * 8 + rowb) * K + (size_t)tt2 * 64 + g8;
        GLDS(src, dst);
        GLDS(src + (size_t)64 * K, dst + 64 * 64);
    };

    f32x4 acc[8][4];
    #pragma unroll
    for (int i = 0; i < 8; ++i)
        #pragma unroll
        for (int j = 0; j < 4; ++j)
            acc[i][j] = (f32x4){0.f, 0.f, 0.f, 0.f};

    const int nt = K >> 6;   // 16

    // prologue: tile0 fully + tile1 A-halves; vmcnt(4) leaves 1.A0/1.A1 in flight
    stageA(0, 0); stageA(0, 1); stageB(0, 0); stageB(0, 1);
    stageA(1, 0); stageA(1, 1);
    asm volatile("s_waitcnt vmcnt(4)" ::: "memory");
    __builtin_amdgcn_sched_barrier(0);
    __builtin_amdgcn_s_barrier();

    for (int tt = 0; tt < nt; ++tt) {
        const unsigned short* lA = la[tt & 1];
        const unsigned short* lB = lb[tt & 1];
        bf16x8 alo[8], ahi[8], blo[4], bhi[4];

        // ---- phase 0: read alo(8)+blo(4); stage T+1.B0; MFMA quad (0,0)
        #pragma unroll
        for (int ks = 0; ks < 2; ++ks) {
            const int pa = ((ks * 4 + lq + lr7) & 7) * 8;
            #pragma unroll
            for (int i = 0; i < 4; ++i)
                alo[ks * 4 + i] = *(const bf16x8*)&lA[(wm + i * 16 + lr) * 64 + pa];
            #pragma unroll
            for (int j = 0; j < 2; ++j)
                blo[ks * 2 + j] = *(const bf16x8*)&lB[(wn + j * 16 + lr) * 64 + pa];
        }
        if (tt + 1 < nt) stageB(tt + 1, 0);
        PH_GATE();
        #pragma unroll
        for (int ks = 0; ks < 2; ++ks)
            #pragma unroll
            for (int i = 0; i < 4; ++i)
                #pragma unroll
                for (int j = 0; j < 2; ++j)
                    acc[i][j] = MFMA16(alo[ks * 4 + i], blo[ks * 2 + j], acc[i][j], 0, 0, 0);
        PH_END();

        // ---- phase 1: read ahi(8); stage T+1.B1; MFMA quad (1,0)
        #pragma unroll
        for (int ks = 0; ks < 2; ++ks) {
            const int pa = ((ks * 4 + lq + lr7) & 7) * 8;
            #pragma unroll
            for (int i = 0; i < 4; ++i)
                ahi[ks * 4 + i] = *(const bf16x8*)&lA[(wm + 64 + i * 16 + lr) * 64 + pa];
        }
        if (tt + 1 < nt) stageB(tt + 1, 1);
        PH_GATE();
        #pragma unroll
        for (int ks = 0; ks < 2; ++ks)
            #pragma unroll
            for (int i = 0; i < 4; ++i)
                #pragma unroll
                for (int j = 0; j < 2; ++j)
                    acc[4 + i][j] = MFMA16(ahi[ks * 4 + i], blo[ks * 2 + j], acc[4 + i][j], 0, 0, 0);
        PH_END();

        // ---- phase 2: read bhi(4); stage T+2.A0 (A rows 0-127 died at ph1); MFMA quad (0,1)
        #pragma unroll
        for (int ks = 0; ks < 2; ++ks) {
            const int pa = ((ks * 4 + lq + lr7) & 7) * 8;
            #pragma unroll
            for (int j = 0; j < 2; ++j)
                bhi[ks * 2 + j] = *(const bf16x8*)&lB[(wn + 32 + j * 16 + lr) * 64 + pa];
        }
        if (tt + 2 < nt) stageA(tt + 2, 0);
        PH_GATE();
        #pragma unroll
        for (int ks = 0; ks < 2; ++ks)
            #pragma unroll
            for (int i = 0; i < 4; ++i)
                #pragma unroll
                for (int j = 0; j < 2; ++j)
                    acc[i][2 + j] = MFMA16(alo[ks * 4 + i], bhi[ks * 2 + j], acc[i][2 + j], 0, 0, 0);
        PH_END();

        // ---- phase 3: no reads; stage T+2.A1; MFMA quad (1,1); counted vmcnt
        if (tt + 2 < nt) stageA(tt + 2, 1);
        __builtin_amdgcn_sched_barrier(0);
        __builtin_amdgcn_s_barrier();
        __builtin_amdgcn_s_setprio(1);
        #pragma unroll
        for (int ks = 0; ks < 2; ++ks)
            #pragma unroll
            for (int i = 0; i < 4; ++i)
                #pragma unroll
                for (int j = 0; j < 2; ++j)
                    acc[4 + i][2 + j] = MFMA16(ahi[ks * 4 + i], bhi[ks * 2 + j], acc[4 + i][2 + j], 0, 0, 0);
        __builtin_amdgcn_s_setprio(0);
        if (tt < nt - 2) {
            // steady: leave T+2.A0/A1 (4 loads) in flight; T+1 fully landed
            asm volatile("s_waitcnt vmcnt(4)" ::: "memory");
        } else if (tt == nt - 2) {
            asm volatile("s_waitcnt vmcnt(0)" ::: "memory");
        }
        __builtin_amdgcn_sched_barrier(0);
        __builtin_amdgcn_s_barrier();
    }

    const float QSCALE = 0.18033688f;  // log2(e)/8, folded into Q
    if (MODE == 0) {
        for (int i = 0; i < 8; ++i)
            for (int j = 0; j < 4; ++j)
                for (int r = 0; r < 4; ++r) {
                    int row = m0 + wm + i * 16 + lq * 4 + r;
                    int col = n0 + wn + j * 16 + lr;
                    Cf[(size_t)row * N + col] = acc[i][j][r];
                }
    } else {
        const int which = n0 >> 10;
        if (which < 2) {
            unsigned short* dst = which ? kb : qb;
            const float sc = which ? 1.0f : QSCALE;
            for (int i = 0; i < 8; ++i)
                for (int j = 0; j < 4; ++j)
                    for (int r = 0; r < 4; ++r) {
                        int row = m0 + wm + i * 16 + lq * 4 + r;
                        int col = n0 + wn + j * 16 + lr;
                        int h = (col >> 6) & 15, d = col & 63;
                        int b = row >> 11, s = row & 2047;
                        dst[((size_t)(b * 16 + h) * 2048 + s) * 64 + d] = f2bf(acc[i][j][r] * sc);
                    }
        } else {
            for (int i = 0; i < 8; ++i) {
                int s0 = m0 + wm + i * 16 + lq * 4;
                int b = s0 >> 11, s = s0 & 2047;
                int4 m4 = *(const int4*)&mask[b * 2048 + s];
                for (int j = 0; j < 4; ++j) {
                    int col = n0 + wn + j * 16 + lr;
                    int h = (col >> 6) & 15, d = col & 63;
                    u16x4 pv;
                    pv[0] = m4.x ? f2bf(acc[i][j][0]) : (unsigned short)0;
                    pv[1] = m4.y ? f2bf(acc[i][j][1]) : (unsigned short)0;
                    pv[2] = m4.z ? f2bf(acc[i][j][2]) : (unsigned short)0;
                    pv[3] = m4.w ? f2bf(acc[i][j][3]) : (unsigned short)0;
                    *(u16x4*)&vt[((size_t)(b * 16 + h) * 64 + d) * 2048 + s] = pv;
                }
            }
        }
    }
}

// Flash attention v12 (unchanged). grid = (64 bh, 8 pairs); block 512 = 8 waves x 16 q;
// two passes over stripes (p, 15-p) => uniform 34 chunk-stages per block.
// XCD = linear%8 = bh%8 -> per-head K/V pinned to one XCD's L2.
__global__ __launch_bounds__(512, 4) void k_attn(
    const unsigned short* __restrict__ qb,
    const unsigned short* __restrict__ kb,
    const unsigned short* __restrict__ vt,
    const unsigned short* __restrict__ maskbg,
    unsigned short* __restrict__ ao)
{
    __shared__ __align__(16) unsigned short kt_lds[2][64 * 64];  // [key][d], d-blocks XOR key&7
    __shared__ __align__(16) unsigned short vt_lds[2][64 * 64];  // [d][key], key-blocks XOR d&7
    __shared__ __align__(16) unsigned short plds[8][16 * 72];    // P[q][key] per wave, stride 72

    const int t = threadIdx.x;
    const int w = t >> 6, lane = t & 63;
    const int lr = lane & 15, lq = lane >> 4;
    const int lr7 = lr & 7;
    const int bh = blockIdx.x, b = bh >> 4, h = bh & 15;

    const unsigned short* qp = qb + (size_t)bh * 2048 * 64;
    const unsigned short* kp = kb + (size_t)bh * 2048 * 64;
    const unsigned short* vp = vt + (size_t)bh * 64 * 2048;
    const unsigned short* mbg = maskbg + b * 2048;
    unsigned short* pw = plds[w];

    const int rowb = lane >> 3, c8 = lane & 7;
    const int sc8 = (c8 ^ rowb) * 8;                 // XOR-swizzled source column block

    auto stage = [&](int c) {
        const int buf = c & 1;
        const int k0 = c * 64;
        const int rg = 8 * w;
        const int row = rg + rowb;
        GLDS(&kp[(size_t)(k0 + row) * 64 + sc8], &kt_lds[buf][rg * 64]);
        GLDS(&vp[(size_t)row * 2048 + k0 + sc8], &vt_lds[buf][rg * 64]);
    };

    for (int pass = 0; pass < 2; ++pass) {
        const int stripe = pass ? (15 - (int)blockIdx.y) : (int)blockIdx.y;
        const int q0w = stripe * 128 + w * 16;

        bf16x8 aq0 = *(const bf16x8*)&qp[(q0w + lr) * 64 + lq * 8];
        bf16x8 aq1 = *(const bf16x8*)&qp[(q0w + lr) * 64 + 32 + lq * 8];

        f32x4 acc[4], lacc;
        lacc = (f32x4){0.f, 0.f, 0.f, 0.f};
        #pragma unroll
        for (int j = 0; j < 4; ++j) acc[j] = (f32x4){0.f, 0.f, 0.f, 0.f};

        const int nch = 2 * (stripe + 1);
        stage(0);
        for (int c = 0; c < nch; ++c) {
            __syncthreads();
            if (c + 1 < nch) stage(c + 1);
            const int k0 = c * 64;
            if (k0 < q0w + 16) {
                const unsigned short* kt = kt_lds[c & 1];
                const unsigned short* vtl = vt_lds[c & 1];
                const bool causal = (k0 + 63 > q0w);
                const int kcol0 = (lq ^ lr7) * 8;
                const int kcol1 = ((4 + lq) ^ lr7) * 8;
                #pragma unroll
                for (int ki = 0; ki < 4; ++ki) {
                    bf16x8 kf0 = *(const bf16x8*)&kt[(ki * 16 + lr) * 64 + kcol0];
                    bf16x8 kf1 = *(const bf16x8*)&kt[(ki * 16 + lr) * 64 + kcol1];
                    f32x4 s = (f32x4){0.f, 0.f, 0.f, 0.f};
                    s = MFMA16(kf0, aq0, s, 0, 0, 0);
                    s = MFMA16(kf1, aq1, s, 0, 0, 0);
                    unsigned int u[4];
                    #pragma unroll
                    for (int r = 0; r < 4; ++r) {
                        float scv = s[r];
                        if (causal) {
                            int key = k0 + ki * 16 + lq * 4 + r;
                            int qq  = q0w + lr;
                            scv = (key <= qq) ? scv : -3.0e38f;
                        }
                        float p = __builtin_amdgcn_exp2f(scv);
                        union { float f; unsigned int u; } cv; cv.f = p;
                        u[r] = cv.u;
                    }
                    uint2 pk;
                    pk.x = __builtin_amdgcn_perm(u[1], u[0], 0x07060302u);
                    pk.y = __builtin_amdgcn_perm(u[3], u[2], 0x07060302u);
                    *(uint2*)&pw[lr * 72 + ki * 16 + lq * 4] = pk;
                }
                #pragma unroll
                for (int kc = 0; kc < 64; kc += 32) {
                    bf16x8 pf = *(const bf16x8*)&pw[lr * 72 + kc + lq * 8];
                    bf16x8 mb = *(const bf16x8*)&mbg[k0 + kc + lq * 8];
                    const int vcol = (((kc >> 3) + lq) ^ lr7) * 8;
                    #pragma unroll
                    for (int j = 0; j < 4; ++j) {
                        bf16x8 vf = *(const bf16x8*)&vtl[(j * 16 + lr) * 64 + vcol];
                        acc[j] = MFMA16(pf, vf, acc[j], 0, 0, 0);
                    }
                    lacc = MFMA16(pf, mb, lacc, 0, 0, 0);
                }
            }
        }

        #pragma unroll
        for (int r = 0; r < 4; ++r) {
            float inv = 1.0f / fmaxf(lacc[r], 1e-30f);
            int row = q0w + lq * 4 + r;
            #pragma unroll
            for (int j = 0; j < 4; ++j) {
                int d = j * 16 + lr;
                ao[(size_t)(b * 2048 + row) * 1024 + h * 64 + d] = f2bf(acc[j][r] * inv);
            }
        }
        __syncthreads();
    }
}

extern "C" void kernel_launch(void* const* d_in, const int* in_sizes, int n_in,
                              void* d_out, int out_size, void* d_ws, size_t ws_size,
                              hipStream_t stream)
{
    const float* x    = (const float*)d_in[0];
    const int*   mask = (const int*)d_in[1];
    const float* wqkv = (const float*)d_in[2];
    const float* wout = (const float*)d_in[3];
    float* out = (float*)d_out;

    const size_t NEED = ((size_t)8192 * 1024 + (size_t)3072 * 1024 + (size_t)1024 * 1024 +
                         3 * (size_t)64 * 2048 * 64 + (size_t)8192 * 1024 + 8192) * 2;
    if (ws_size < NEED) return;

    char* ws = (char*)d_ws;
    unsigned short* xb  = (unsigned short*)ws; ws += (size_t)8192 * 1024 * 2;
    unsigned short* w1t = (unsigned short*)ws; ws += (size_t)3072 * 1024 * 2;
    unsigned short* w2t = (unsigned short*)ws; ws += (size_t)1024 * 1024 * 2;
    unsigned short* qb  = (unsigned short*)ws; ws += (size_t)64 * 2048 * 64 * 2;
    unsigned short* kb  = (unsigned short*)ws; ws += (size_t)64 * 2048 * 64 * 2;
    unsigned short* vt  = (unsigned short*)ws; ws += (size_t)64 * 64 * 2048 * 2;
    unsigned short* ao  = (unsigned short*)ws; ws += (size_t)8192 * 1024 * 2;
    unsigned short* mbg = (unsigned short*)ws; ws += (size_t)8192 * 2;

    k_prep<<<dim3(8192), 256, 0, stream>>>(x, xb, mask, mbg, wqkv, w1t, wout, w2t);
    k_gemm256<1, 12><<<dim3(12, 32), 512, 0, stream>>>(xb, w1t, nullptr, qb, kb, vt, mask, 3072, 1024);
    k_attn<<<dim3(64, 8), 512, 0, stream>>>(qb, kb, vt, mbg, ao);
    k_gemm256<0, 4><<<dim3(4, 32), 512, 0, stream>>>(ao, w2t, out, nullptr, nullptr, nullptr, nullptr, 1024, 1024);
}

// Round 3
// 254.357 us; speedup vs baseline: 1.0089x; 1.0089x over previous
//
#include <hip/hip_runtime.h>

// MHA forward: B=4, S=2048, D=1024, H=16, hd=64, causal+pad mask, scale=8.
// IO fp32; internal bf16 MFMA with fp32 accumulate.
// v15 = GEMMs reverted to the PROVEN v12 k_gemm_bt (128x128, 256 thr,
// ~5 blocks/CU TLP, 68us QKV measured; the 8-phase ports v13/v14 regressed
// 76/95us — abandoned). Attention rebuilt for LDS-read amortization:
// 4 waves x 32 q-rows (was 8 x 16), K/V fragments read once per wave and
// reused across both 16-row q-groups -> per-CU LDS read traffic per chunk
// 320KB -> 176KB for the same MFMA work. Grid/stripes/staging/swizzles
// identical to v12; only wave->row mapping and stage lambda changed.

typedef __attribute__((ext_vector_type(8))) short bf16x8;
typedef __attribute__((ext_vector_type(8))) unsigned short u16x8;
typedef __attribute__((ext_vector_type(4))) unsigned short u16x4;
typedef __attribute__((ext_vector_type(4))) float f32x4;

#define MFMA16 __builtin_amdgcn_mfma_f32_16x16x32_bf16

#define GLDS(gp, lp) __builtin_amdgcn_global_load_lds( \
    (const __attribute__((address_space(1))) unsigned int*)(gp), \
    (__attribute__((address_space(3))) unsigned int*)(lp), 16, 0, 0)

__device__ __forceinline__ unsigned short f2bf(float f) {
    union { float f; unsigned int u; } v; v.f = f;
    unsigned int r = v.u + 0x7fffu + ((v.u >> 16) & 1u);
    return (unsigned short)(r >> 16);
}

// bx<4096: fp32->bf16 x-convert (+mask->bf16 in first 32 blocks).
// bx>=4096: weight transposes (w_qkv 1024x3072, w_out 1024x1024).
__global__ void k_prep(const float* __restrict__ x, unsigned short* __restrict__ xb,
                       const int* __restrict__ mask, unsigned short* __restrict__ mb,
                       const float* __restrict__ wqkv, unsigned short* __restrict__ w1t,
                       const float* __restrict__ wout, unsigned short* __restrict__ w2t) {
    __shared__ float tile[32][33];
    const int bx = blockIdx.x;
    if (bx < 4096) {
        size_t i = ((size_t)bx * 256 + threadIdx.x) * 8;
        float4 f0 = *(const float4*)(x + i);
        float4 f1 = *(const float4*)(x + i + 4);
        u16x8 v;
        v[0] = f2bf(f0.x); v[1] = f2bf(f0.y); v[2] = f2bf(f0.z); v[3] = f2bf(f0.w);
        v[4] = f2bf(f1.x); v[5] = f2bf(f1.y); v[6] = f2bf(f1.z); v[7] = f2bf(f1.w);
        *(u16x8*)(xb + i) = v;
        if (bx < 32) {
            int j = bx * 256 + threadIdx.x;
            mb[j] = mask[j] ? (unsigned short)0x3F80 : (unsigned short)0;
        }
    } else {
        const int b2 = bx - 4096;
        const int cb = b2 & 127, rb = b2 >> 7;
        const float* in = (cb < 96) ? wqkv : wout;
        unsigned short* out = (cb < 96) ? w1t : w2t;
        const int C = (cb < 96) ? 3072 : 1024;
        const int c0 = ((cb < 96) ? cb : cb - 96) * 32;
        const int r0 = rb * 32;
        int tx = threadIdx.x & 31, ty = threadIdx.x >> 5;
        for (int i = ty; i < 32; i += 8)
            tile[i][tx] = in[(size_t)(r0 + i) * C + (c0 + tx)];
        __syncthreads();
        for (int i = ty; i < 32; i += 8)
            out[(size_t)(c0 + i) * 1024 + (r0 + tx)] = f2bf(tile[tx][i]);
    }
}

// C[M][N] = A[M][K] * Bt[N][K]^T.  128x128 tile, BK=64, swizzled LDS (v8/v12, unchanged).
template <int MODE>
__global__ __launch_bounds__(256) void k_gemm_bt(
    const unsigned short* __restrict__ Ab,
    const unsigned short* __restrict__ Bt,
    float* __restrict__ Cf,
    unsigned short* __restrict__ qb,
    unsigned short* __restrict__ kb,
    unsigned short* __restrict__ vt,
    const int* __restrict__ mask,
    int N, int K)
{
    __shared__ __align__(16) unsigned short la[128 * 64];
    __shared__ __align__(16) unsigned short lb[128 * 64];
    const int t = threadIdx.x;
    const int m0 = blockIdx.y * 128, n0 = blockIdx.x * 128;
    const int w = t >> 6, lane = t & 63;
    const int wm = (w & 1) * 64, wn = (w >> 1) * 64;
    const int lr = lane & 15, lq = lane >> 4;
    const int lr7 = lr & 7;
    const int rowb = lane >> 3;
    const int g8 = (((lane & 7) - rowb) & 7) * 8;

    f32x4 acc[4][4];
    for (int i = 0; i < 4; ++i)
        for (int j = 0; j < 4; ++j)
            acc[i][j] = (f32x4){0.f, 0.f, 0.f, 0.f};

    for (int k0 = 0; k0 < K; k0 += 64) {
        #pragma unroll
        for (int r = 0; r < 4; ++r) {
            const int rg = w * 8 + r * 32;
            GLDS(&Ab[(size_t)(m0 + rg + rowb) * K + k0 + g8], &la[rg * 64]);
            GLDS(&Bt[(size_t)(n0 + rg + rowb) * K + k0 + g8], &lb[rg * 64]);
        }
        __syncthreads();
        #pragma unroll
        for (int ks = 0; ks < 2; ++ks) {
            const int pa = ((ks * 4 + lq + lr7) & 7) * 8;
            bf16x8 af[4], bg[4];
            #pragma unroll
            for (int i = 0; i < 4; ++i) {
                af[i] = *(const bf16x8*)&la[(wm + i * 16 + lr) * 64 + pa];
                bg[i] = *(const bf16x8*)&lb[(wn + i * 16 + lr) * 64 + pa];
            }
            #pragma unroll
            for (int i = 0; i < 4; ++i)
                #pragma unroll
                for (int j = 0; j < 4; ++j)
                    acc[i][j] = MFMA16(af[i], bg[j], acc[i][j], 0, 0, 0);
        }
        __syncthreads();
    }

    const float QSCALE = 0.18033688f;  // log2(e)/8, folded into Q
    if (MODE == 0) {
        for (int i = 0; i < 4; ++i)
            for (int j = 0; j < 4; ++j)
                for (int r = 0; r < 4; ++r) {
                    int row = m0 + wm + i * 16 + lq * 4 + r;
                    int col = n0 + wn + j * 16 + lr;
                    Cf[(size_t)row * N + col] = acc[i][j][r];
                }
    } else {
        const int which = n0 >> 10;
        if (which < 2) {
            unsigned short* dst = which ? kb : qb;
            const float sc = which ? 1.0f : QSCALE;
            for (int i = 0; i < 4; ++i)
                for (int j = 0; j < 4; ++j)
                    for (int r = 0; r < 4; ++r) {
                        int row = m0 + wm + i * 16 + lq * 4 + r;
                        int col = n0 + wn + j * 16 + lr;
                        int h = (col >> 6) & 15, d = col & 63;
                        int b = row >> 11, s = row & 2047;
                        dst[((size_t)(b * 16 + h) * 2048 + s) * 64 + d] = f2bf(acc[i][j][r] * sc);
                    }
        } else {
            for (int i = 0; i < 4; ++i) {
                int s0 = m0 + wm + i * 16 + lq * 4;
                int b = s0 >> 11, s = s0 & 2047;
                int4 m4 = *(const int4*)&mask[b * 2048 + s];
                for (int j = 0; j < 4; ++j) {
                    int col = n0 + wn + j * 16 + lr;
                    int h = (col >> 6) & 15, d = col & 63;
                    u16x4 pv;
                    pv[0] = m4.x ? f2bf(acc[i][j][0]) : (unsigned short)0;
                    pv[1] = m4.y ? f2bf(acc[i][j][1]) : (unsigned short)0;
                    pv[2] = m4.z ? f2bf(acc[i][j][2]) : (unsigned short)0;
                    pv[3] = m4.w ? f2bf(acc[i][j][3]) : (unsigned short)0;
                    *(u16x4*)&vt[((size_t)(b * 16 + h) * 64 + d) * 2048 + s] = pv;
                }
            }
        }
    }
}

// Flash attention v15. grid = (64 bh, 8 pairs); block 256 = 4 waves x 32 q;
// two passes over stripes (p, 15-p) => uniform 34 chunk-stages per block.
// XCD = linear%8 = bh%8 -> per-head K/V pinned to one XCD L2.
// K/V LDS fragments read ONCE per wave, reused across both 16-row q-groups.
__global__ __launch_bounds__(256, 2) void k_attn(
    const unsigned short* __restrict__ qb,
    const unsigned short* __restrict__ kb,
    const unsigned short* __restrict__ vt,
    const unsigned short* __restrict__ maskbg,
    unsigned short* __restrict__ ao)
{
    __shared__ __align__(16) unsigned short kt_lds[2][64 * 64];  // [key][d], d-blocks XOR key&7
    __shared__ __align__(16) unsigned short vt_lds[2][64 * 64];  // [d][key], key-blocks XOR d&7
    __shared__ __align__(16) unsigned short plds[4][32 * 72];    // P[q][key] per wave, stride 72

    const int t = threadIdx.x;
    const int w = t >> 6, lane = t & 63;   // w in 0..3
    const int lr = lane & 15, lq = lane >> 4;
    const int lr7 = lr & 7;
    const int bh = blockIdx.x, b = bh >> 4, h = bh & 15;

    const unsigned short* qp = qb + (size_t)bh * 2048 * 64;
    const unsigned short* kp = kb + (size_t)bh * 2048 * 64;
    const unsigned short* vp = vt + (size_t)bh * 64 * 2048;
    const unsigned short* mbg = maskbg + b * 2048;
    unsigned short* pw = plds[w];

    const int rowb = lane >> 3, c8 = lane & 7;
    const int sc8 = (c8 ^ rowb) * 8;                 // XOR-swizzled source column block

    // each wave stages 16 K-rows and 16 V-rows (2 GLDS each)
    auto stage = [&](int c) {
        const int buf = c & 1;
        const int k0 = c * 64;
        const int rg = 16 * w;
        const int row = rg + rowb;
        GLDS(&kp[(size_t)(k0 + row) * 64 + sc8],       &kt_lds[buf][rg * 64]);
        GLDS(&kp[(size_t)(k0 + row + 8) * 64 + sc8],   &kt_lds[buf][(rg + 8) * 64]);
        GLDS(&vp[(size_t)row * 2048 + k0 + sc8],       &vt_lds[buf][rg * 64]);
        GLDS(&vp[(size_t)(row + 8) * 2048 + k0 + sc8], &vt_lds[buf][(rg + 8) * 64]);
    };

    for (int pass = 0; pass < 2; ++pass) {
        const int stripe = pass ? (15 - (int)blockIdx.y) : (int)blockIdx.y;
        const int q0w = stripe * 128 + w * 32;

        bf16x8 aq00 = *(const bf16x8*)&qp[(q0w + lr) * 64 + lq * 8];
        bf16x8 aq01 = *(const bf16x8*)&qp[(q0w + lr) * 64 + 32 + lq * 8];
        bf16x8 aq10 = *(const bf16x8*)&qp[(q0w + 16 + lr) * 64 + lq * 8];
        bf16x8 aq11 = *(const bf16x8*)&qp[(q0w + 16 + lr) * 64 + 32 + lq * 8];

        f32x4 acc[2][4], lacc[2];
        #pragma unroll
        for (int g = 0; g < 2; ++g) {
            lacc[g] = (f32x4){0.f, 0.f, 0.f, 0.f};
            #pragma unroll
            for (int j = 0; j < 4; ++j) acc[g][j] = (f32x4){0.f, 0.f, 0.f, 0.f};
        }

        const int nch = 2 * (stripe + 1);
        stage(0);
        for (int c = 0; c < nch; ++c) {
            __syncthreads();
            if (c + 1 < nch) stage(c + 1);
            const int k0 = c * 64;
            if (k0 < q0w + 32) {
                const unsigned short* kt = kt_lds[c & 1];
                const unsigned short* vtl = vt_lds[c & 1];
                const bool causal = (k0 + 63 > q0w);
                const int kcol0 = (lq ^ lr7) * 8;
                const int kcol1 = ((4 + lq) ^ lr7) * 8;
                #pragma unroll
                for (int ki = 0; ki < 4; ++ki) {
                    bf16x8 kf0 = *(const bf16x8*)&kt[(ki * 16 + lr) * 64 + kcol0];
                    bf16x8 kf1 = *(const bf16x8*)&kt[(ki * 16 + lr) * 64 + kcol1];
                    #pragma unroll
                    for (int g = 0; g < 2; ++g) {
                        f32x4 s = (f32x4){0.f, 0.f, 0.f, 0.f};
                        s = MFMA16(kf0, g ? aq10 : aq00, s, 0, 0, 0);
                        s = MFMA16(kf1, g ? aq11 : aq01, s, 0, 0, 0);
                        unsigned int u[4];
                        #pragma unroll
                        for (int r = 0; r < 4; ++r) {
                            float scv = s[r];
                            if (causal) {
                                int key = k0 + ki * 16 + lq * 4 + r;
                                int qq  = q0w + g * 16 + lr;
                                scv = (key <= qq) ? scv : -3.0e38f;
                            }
                            float p = __builtin_amdgcn_exp2f(scv);
                            union { float f; unsigned int u; } cv; cv.f = p;
                            u[r] = cv.u;
                        }
                        uint2 pk;
                        pk.x = __builtin_amdgcn_perm(u[1], u[0], 0x07060302u);
                        pk.y = __builtin_amdgcn_perm(u[3], u[2], 0x07060302u);
                        *(uint2*)&pw[(g * 16 + lr) * 72 + ki * 16 + lq * 4] = pk;
                    }
                }
                #pragma unroll
                for (int kc = 0; kc < 64; kc += 32) {
                    bf16x8 mb = *(const bf16x8*)&mbg[k0 + kc + lq * 8];
                    const int vcol = (((kc >> 3) + lq) ^ lr7) * 8;
                    bf16x8 vf[4];
                    #pragma unroll
                    for (int j = 0; j < 4; ++j)
                        vf[j] = *(const bf16x8*)&vtl[(j * 16 + lr) * 64 + vcol];
                    #pragma unroll
                    for (int g = 0; g < 2; ++g) {
                        bf16x8 pf = *(const bf16x8*)&pw[(g * 16 + lr) * 72 + kc + lq * 8];
                        #pragma unroll
                        for (int j = 0; j < 4; ++j)
                            acc[g][j] = MFMA16(pf, vf[j], acc[g][j], 0, 0, 0);
                        lacc[g] = MFMA16(pf, mb, lacc[g], 0, 0, 0);
                    }
                }
            }
        }

        #pragma unroll
        for (int g = 0; g < 2; ++g)
            #pragma unroll
            for (int r = 0; r < 4; ++r) {
                float inv = 1.0f / fmaxf(lacc[g][r], 1e-30f);
                int row = q0w + g * 16 + lq * 4 + r;
                #pragma unroll
                for (int j = 0; j < 4; ++j) {
                    int d = j * 16 + lr;
                    ao[(size_t)(b * 2048 + row) * 1024 + h * 64 + d] = f2bf(acc[g][j][r] * inv);
                }
            }
        __syncthreads();
    }
}

extern "C" void kernel_launch(void* const* d_in, const int* in_sizes, int n_in,
                              void* d_out, int out_size, void* d_ws, size_t ws_size,
                              hipStream_t stream)
{
    const float* x    = (const float*)d_in[0];
    const int*   mask = (const int*)d_in[1];
    const float* wqkv = (const float*)d_in[2];
    const float* wout = (const float*)d_in[3];
    float* out = (float*)d_out;

    const size_t NEED = ((size_t)8192 * 1024 + (size_t)3072 * 1024 + (size_t)1024 * 1024 +
                         3 * (size_t)64 * 2048 * 64 + (size_t)8192 * 1024 + 8192) * 2;
    if (ws_size < NEED) return;

    char* ws = (char*)d_ws;
    unsigned short* xb  = (unsigned short*)ws; ws += (size_t)8192 * 1024 * 2;
    unsigned short* w1t = (unsigned short*)ws; ws += (size_t)3072 * 1024 * 2;
    unsigned short* w2t = (unsigned short*)ws; ws += (size_t)1024 * 1024 * 2;
    unsigned short* qb  = (unsigned short*)ws; ws += (size_t)64 * 2048 * 64 * 2;
    unsigned short* kb  = (unsigned short*)ws; ws += (size_t)64 * 2048 * 64 * 2;
    unsigned short* vt  = (unsigned short*)ws; ws += (size_t)64 * 64 * 2048 * 2;
    unsigned short* ao  = (unsigned short*)ws; ws += (size_t)8192 * 1024 * 2;
    unsigned short* mbg = (unsigned short*)ws; ws += (size_t)8192 * 2;

    k_prep<<<dim3(8192), 256, 0, stream>>>(x, xb, mask, mbg, wqkv, w1t, wout, w2t);
    k_gemm_bt<1><<<dim3(24, 64), 256, 0, stream>>>(xb, w1t, nullptr, qb, kb, vt, mask, 3072, 1024);
    k_attn<<<dim3(64, 8), 256, 0, stream>>>(qb, kb, vt, mbg, ao);
    k_gemm_bt<0><<<dim3(8, 64), 256, 0, stream>>>(ao, w2t, out, nullptr, nullptr, nullptr, nullptr, 1024, 1024);
}

// Round 4
// 244.567 us; speedup vs baseline: 1.0493x; 1.0400x over previous
//
#include <hip/hip_runtime.h>

// MHA forward: B=4, S=2048, D=1024, H=16, hd=64, causal+pad mask, scale=8.
// IO fp32; internal bf16 MFMA with fp32 accumulate.
// v16 = full revert to the proven v12 structure (GEMM 128x128/256thr;
// attn 512thr = 8 waves x 16 q, grid (64,8), double-buffered XOR-swizzled
// K/V staging, XCD pinning bh%8) + ONE fix: P-scratch LDS re-layout.
// Old P rows stride 72 shorts (144B): uint2 writes hit only 16 even banks
// -> 8 phases vs 4 min -> ~2.2M conflict cycles/dispatch (measured 3.24M
// total in v15, same pattern). New: stride 64, 16B-unit c stored at
// c ^ (lr&7); writes land on all 32 banks uniformly (4-phase minimum),
// reads stay at the 8-phase minimum. Saves 2.4KB LDS too.

typedef __attribute__((ext_vector_type(8))) short bf16x8;
typedef __attribute__((ext_vector_type(8))) unsigned short u16x8;
typedef __attribute__((ext_vector_type(4))) unsigned short u16x4;
typedef __attribute__((ext_vector_type(4))) float f32x4;

#define MFMA16 __builtin_amdgcn_mfma_f32_16x16x32_bf16

#define GLDS(gp, lp) __builtin_amdgcn_global_load_lds( \
    (const __attribute__((address_space(1))) unsigned int*)(gp), \
    (__attribute__((address_space(3))) unsigned int*)(lp), 16, 0, 0)

__device__ __forceinline__ unsigned short f2bf(float f) {
    union { float f; unsigned int u; } v; v.f = f;
    unsigned int r = v.u + 0x7fffu + ((v.u >> 16) & 1u);
    return (unsigned short)(r >> 16);
}

// bx<4096: fp32->bf16 x-convert (+mask->bf16 in first 32 blocks).
// bx>=4096: weight transposes (w_qkv 1024x3072, w_out 1024x1024).
__global__ void k_prep(const float* __restrict__ x, unsigned short* __restrict__ xb,
                       const int* __restrict__ mask, unsigned short* __restrict__ mb,
                       const float* __restrict__ wqkv, unsigned short* __restrict__ w1t,
                       const float* __restrict__ wout, unsigned short* __restrict__ w2t) {
    __shared__ float tile[32][33];
    const int bx = blockIdx.x;
    if (bx < 4096) {
        size_t i = ((size_t)bx * 256 + threadIdx.x) * 8;
        float4 f0 = *(const float4*)(x + i);
        float4 f1 = *(const float4*)(x + i + 4);
        u16x8 v;
        v[0] = f2bf(f0.x); v[1] = f2bf(f0.y); v[2] = f2bf(f0.z); v[3] = f2bf(f0.w);
        v[4] = f2bf(f1.x); v[5] = f2bf(f1.y); v[6] = f2bf(f1.z); v[7] = f2bf(f1.w);
        *(u16x8*)(xb + i) = v;
        if (bx < 32) {
            int j = bx * 256 + threadIdx.x;
            mb[j] = mask[j] ? (unsigned short)0x3F80 : (unsigned short)0;
        }
    } else {
        const int b2 = bx - 4096;
        const int cb = b2 & 127, rb = b2 >> 7;
        const float* in = (cb < 96) ? wqkv : wout;
        unsigned short* out = (cb < 96) ? w1t : w2t;
        const int C = (cb < 96) ? 3072 : 1024;
        const int c0 = ((cb < 96) ? cb : cb - 96) * 32;
        const int r0 = rb * 32;
        int tx = threadIdx.x & 31, ty = threadIdx.x >> 5;
        for (int i = ty; i < 32; i += 8)
            tile[i][tx] = in[(size_t)(r0 + i) * C + (c0 + tx)];
        __syncthreads();
        for (int i = ty; i < 32; i += 8)
            out[(size_t)(c0 + i) * 1024 + (r0 + tx)] = f2bf(tile[tx][i]);
    }
}

// C[M][N] = A[M][K] * Bt[N][K]^T.  128x128 tile, BK=64, swizzled LDS (v8/v12, unchanged).
template <int MODE>
__global__ __launch_bounds__(256) void k_gemm_bt(
    const unsigned short* __restrict__ Ab,
    const unsigned short* __restrict__ Bt,
    float* __restrict__ Cf,
    unsigned short* __restrict__ qb,
    unsigned short* __restrict__ kb,
    unsigned short* __restrict__ vt,
    const int* __restrict__ mask,
    int N, int K)
{
    __shared__ __align__(16) unsigned short la[128 * 64];
    __shared__ __align__(16) unsigned short lb[128 * 64];
    const int t = threadIdx.x;
    const int m0 = blockIdx.y * 128, n0 = blockIdx.x * 128;
    const int w = t >> 6, lane = t & 63;
    const int wm = (w & 1) * 64, wn = (w >> 1) * 64;
    const int lr = lane & 15, lq = lane >> 4;
    const int lr7 = lr & 7;
    const int rowb = lane >> 3;
    const int g8 = (((lane & 7) - rowb) & 7) * 8;

    f32x4 acc[4][4];
    for (int i = 0; i < 4; ++i)
        for (int j = 0; j < 4; ++j)
            acc[i][j] = (f32x4){0.f, 0.f, 0.f, 0.f};

    for (int k0 = 0; k0 < K; k0 += 64) {
        #pragma unroll
        for (int r = 0; r < 4; ++r) {
            const int rg = w * 8 + r * 32;
            GLDS(&Ab[(size_t)(m0 + rg + rowb) * K + k0 + g8], &la[rg * 64]);
            GLDS(&Bt[(size_t)(n0 + rg + rowb) * K + k0 + g8], &lb[rg * 64]);
        }
        __syncthreads();
        #pragma unroll
        for (int ks = 0; ks < 2; ++ks) {
            const int pa = ((ks * 4 + lq + lr7) & 7) * 8;
            bf16x8 af[4], bg[4];
            #pragma unroll
            for (int i = 0; i < 4; ++i) {
                af[i] = *(const bf16x8*)&la[(wm + i * 16 + lr) * 64 + pa];
                bg[i] = *(const bf16x8*)&lb[(wn + i * 16 + lr) * 64 + pa];
            }
            #pragma unroll
            for (int i = 0; i < 4; ++i)
                #pragma unroll
                for (int j = 0; j < 4; ++j)
                    acc[i][j] = MFMA16(af[i], bg[j], acc[i][j], 0, 0, 0);
        }
        __syncthreads();
    }

    const float QSCALE = 0.18033688f;  // log2(e)/8, folded into Q
    if (MODE == 0) {
        for (int i = 0; i < 4; ++i)
            for (int j = 0; j < 4; ++j)
                for (int r = 0; r < 4; ++r) {
                    int row = m0 + wm + i * 16 + lq * 4 + r;
                    int col = n0 + wn + j * 16 + lr;
                    Cf[(size_t)row * N + col] = acc[i][j][r];
                }
    } else {
        const int which = n0 >> 10;
        if (which < 2) {
            unsigned short* dst = which ? kb : qb;
            const float sc = which ? 1.0f : QSCALE;
            for (int i = 0; i < 4; ++i)
                for (int j = 0; j < 4; ++j)
                    for (int r = 0; r < 4; ++r) {
                        int row = m0 + wm + i * 16 + lq * 4 + r;
                        int col = n0 + wn + j * 16 + lr;
                        int h = (col >> 6) & 15, d = col & 63;
                        int b = row >> 11, s = row & 2047;
                        dst[((size_t)(b * 16 + h) * 2048 + s) * 64 + d] = f2bf(acc[i][j][r] * sc);
                    }
        } else {
            for (int i = 0; i < 4; ++i) {
                int s0 = m0 + wm + i * 16 + lq * 4;
                int b = s0 >> 11, s = s0 & 2047;
                int4 m4 = *(const int4*)&mask[b * 2048 + s];
                for (int j = 0; j < 4; ++j) {
                    int col = n0 + wn + j * 16 + lr;
                    int h = (col >> 6) & 15, d = col & 63;
                    u16x4 pv;
                    pv[0] = m4.x ? f2bf(acc[i][j][0]) : (unsigned short)0;
                    pv[1] = m4.y ? f2bf(acc[i][j][1]) : (unsigned short)0;
                    pv[2] = m4.z ? f2bf(acc[i][j][2]) : (unsigned short)0;
                    pv[3] = m4.w ? f2bf(acc[i][j][3]) : (unsigned short)0;
                    *(u16x4*)&vt[((size_t)(b * 16 + h) * 64 + d) * 2048 + s] = pv;
                }
            }
        }
    }
}

// Flash attention v16 = v12 body + conflict-free P-scratch layout.
// grid = (64 bh, 8 pairs); block 512 = 8 waves x 16 q; two passes over
// stripes (p, 15-p) => uniform 34 chunk-stages per block.
// XCD = linear%8 = bh%8 -> per-head K/V pinned to one XCD's L2.
// P row = 64 shorts; 16B-unit c stored at (c ^ (lr&7)) -> uniform banks.
__global__ __launch_bounds__(512, 4) void k_attn(
    const unsigned short* __restrict__ qb,
    const unsigned short* __restrict__ kb,
    const unsigned short* __restrict__ vt,
    const unsigned short* __restrict__ maskbg,
    unsigned short* __restrict__ ao)
{
    __shared__ __align__(16) unsigned short kt_lds[2][64 * 64];  // [key][d], d-blocks XOR key&7
    __shared__ __align__(16) unsigned short vt_lds[2][64 * 64];  // [d][key], key-blocks XOR d&7
    __shared__ __align__(16) unsigned short plds[8][16 * 64];    // P[q][key] per wave, slot-swizzled

    const int t = threadIdx.x;
    const int w = t >> 6, lane = t & 63;
    const int lr = lane & 15, lq = lane >> 4;
    const int lr7 = lr & 7;
    const int bh = blockIdx.x, b = bh >> 4, h = bh & 15;

    const unsigned short* qp = qb + (size_t)bh * 2048 * 64;
    const unsigned short* kp = kb + (size_t)bh * 2048 * 64;
    const unsigned short* vp = vt + (size_t)bh * 64 * 2048;
    const unsigned short* mbg = maskbg + b * 2048;
    unsigned short* pw = plds[w];

    const int rowb = lane >> 3, c8 = lane & 7;
    const int sc8 = (c8 ^ rowb) * 8;                 // XOR-swizzled source column block

    auto stage = [&](int c) {
        const int buf = c & 1;
        const int k0 = c * 64;
        const int rg = 8 * w;
        const int row = rg + rowb;
        GLDS(&kp[(size_t)(k0 + row) * 64 + sc8], &kt_lds[buf][rg * 64]);
        GLDS(&vp[(size_t)row * 2048 + k0 + sc8], &vt_lds[buf][rg * 64]);
    };

    for (int pass = 0; pass < 2; ++pass) {
        const int stripe = pass ? (15 - (int)blockIdx.y) : (int)blockIdx.y;
        const int q0w = stripe * 128 + w * 16;

        bf16x8 aq0 = *(const bf16x8*)&qp[(q0w + lr) * 64 + lq * 8];
        bf16x8 aq1 = *(const bf16x8*)&qp[(q0w + lr) * 64 + 32 + lq * 8];

        f32x4 acc[4], lacc;
        lacc = (f32x4){0.f, 0.f, 0.f, 0.f};
        #pragma unroll
        for (int j = 0; j < 4; ++j) acc[j] = (f32x4){0.f, 0.f, 0.f, 0.f};

        const int nch = 2 * (stripe + 1);
        stage(0);
        for (int c = 0; c < nch; ++c) {
            __syncthreads();
            if (c + 1 < nch) stage(c + 1);
            const int k0 = c * 64;
            if (k0 < q0w + 16) {
                const unsigned short* kt = kt_lds[c & 1];
                const unsigned short* vtl = vt_lds[c & 1];
                const bool causal = (k0 + 63 > q0w);
                const int kcol0 = (lq ^ lr7) * 8;
                const int kcol1 = ((4 + lq) ^ lr7) * 8;
                #pragma unroll
                for (int ki = 0; ki < 4; ++ki) {
                    bf16x8 kf0 = *(const bf16x8*)&kt[(ki * 16 + lr) * 64 + kcol0];
                    bf16x8 kf1 = *(const bf16x8*)&kt[(ki * 16 + lr) * 64 + kcol1];
                    f32x4 s = (f32x4){0.f, 0.f, 0.f, 0.f};
                    s = MFMA16(kf0, aq0, s, 0, 0, 0);
                    s = MFMA16(kf1, aq1, s, 0, 0, 0);
                    unsigned int u[4];
                    #pragma unroll
                    for (int r = 0; r < 4; ++r) {
                        float scv = s[r];
                        if (causal) {
                            int key = k0 + ki * 16 + lq * 4 + r;
                            int qq  = q0w + lr;
                            scv = (key <= qq) ? scv : -3.0e38f;
                        }
                        float p = __builtin_amdgcn_exp2f(scv);
                        union { float f; unsigned int u; } cv; cv.f = p;
                        u[r] = cv.u;
                    }
                    uint2 pk;
                    pk.x = __builtin_amdgcn_perm(u[1], u[0], 0x07060302u);
                    pk.y = __builtin_amdgcn_perm(u[3], u[2], 0x07060302u);
                    // P slot-swizzle: 16B-unit c = ki*2+(lq>>1), half = lq&1,
                    // stored at unit (c ^ lr7)  -> write banks uniform (4-phase min)
                    *(uint2*)&pw[lr * 64 + (((ki * 2 + (lq >> 1)) ^ lr7) * 8) + (lq & 1) * 4] = pk;
                }
                #pragma unroll
                for (int kc = 0; kc < 64; kc += 32) {
                    // read 16B-unit c = kc/8 + lq at swizzled slot (c ^ lr7)
                    bf16x8 pf = *(const bf16x8*)&pw[lr * 64 + ((((kc >> 3) + lq) ^ lr7) * 8)];
                    bf16x8 mb = *(const bf16x8*)&mbg[k0 + kc + lq * 8];
                    const int vcol = (((kc >> 3) + lq) ^ lr7) * 8;
                    #pragma unroll
                    for (int j = 0; j < 4; ++j) {
                        bf16x8 vf = *(const bf16x8*)&vtl[(j * 16 + lr) * 64 + vcol];
                        acc[j] = MFMA16(pf, vf, acc[j], 0, 0, 0);
                    }
                    lacc = MFMA16(pf, mb, lacc, 0, 0, 0);
                }
            }
        }

        #pragma unroll
        for (int r = 0; r < 4; ++r) {
            float inv = 1.0f / fmaxf(lacc[r], 1e-30f);
            int row = q0w + lq * 4 + r;
            #pragma unroll
            for (int j = 0; j < 4; ++j) {
                int d = j * 16 + lr;
                ao[(size_t)(b * 2048 + row) * 1024 + h * 64 + d] = f2bf(acc[j][r] * inv);
            }
        }
        __syncthreads();
    }
}

extern "C" void kernel_launch(void* const* d_in, const int* in_sizes, int n_in,
                              void* d_out, int out_size, void* d_ws, size_t ws_size,
                              hipStream_t stream)
{
    const float* x    = (const float*)d_in[0];
    const int*   mask = (const int*)d_in[1];
    const float* wqkv = (const float*)d_in[2];
    const float* wout = (const float*)d_in[3];
    float* out = (float*)d_out;

    const size_t NEED = ((size_t)8192 * 1024 + (size_t)3072 * 1024 + (size_t)1024 * 1024 +
                         3 * (size_t)64 * 2048 * 64 + (size_t)8192 * 1024 + 8192) * 2;
    if (ws_size < NEED) return;

    char* ws = (char*)d_ws;
    unsigned short* xb  = (unsigned short*)ws; ws += (size_t)8192 * 1024 * 2;
    unsigned short* w1t = (unsigned short*)ws; ws += (size_t)3072 * 1024 * 2;
    unsigned short* w2t = (unsigned short*)ws; ws += (size_t)1024 * 1024 * 2;
    unsigned short* qb  = (unsigned short*)ws; ws += (size_t)64 * 2048 * 64 * 2;
    unsigned short* kb  = (unsigned short*)ws; ws += (size_t)64 * 2048 * 64 * 2;
    unsigned short* vt  = (unsigned short*)ws; ws += (size_t)64 * 64 * 2048 * 2;
    unsigned short* ao  = (unsigned short*)ws; ws += (size_t)8192 * 1024 * 2;
    unsigned short* mbg = (unsigned short*)ws; ws += (size_t)8192 * 2;

    k_prep<<<dim3(8192), 256, 0, stream>>>(x, xb, mask, mbg, wqkv, w1t, wout, w2t);
    k_gemm_bt<1><<<dim3(24, 64), 256, 0, stream>>>(xb, w1t, nullptr, qb, kb, vt, mask, 3072, 1024);
    k_attn<<<dim3(64, 8), 512, 0, stream>>>(qb, kb, vt, mbg, ao);
    k_gemm_bt<0><<<dim3(8, 64), 256, 0, stream>>>(ao, w2t, out, nullptr, nullptr, nullptr, nullptr, 1024, 1024);
}

// Round 5
// 244.423 us; speedup vs baseline: 1.0499x; 1.0006x over previous
//
#include <hip/hip_runtime.h>

// MHA forward: B=4, S=2048, D=1024, H=16, hd=64, causal+pad mask, scale=8.
// IO fp32; internal bf16 MFMA with fp32 accumulate.
// v17 = v16 GEMMs/prep unchanged; attn occupancy fix: v16 measured
// Occupancy 36.6% (grid 512 = exactly 2 blocks/CU; LDS 48KB allows 3).
// Drop the stripe-pair pass loop -> ONE stripe per block, grid (64,16) =
// 1024 blocks, stripe = 15 - blockIdx.y (big stripes dispatch first, LPT
// packing). Attn chunk body byte-identical to v16 (conflict-free P slot
// swizzle, double-buffered XOR-swizzled K/V staging). XCD pin preserved
// (linear%8 = bh%8). Predicted: attn 71.4 -> ~56-62us, occ -> ~55-65%.

typedef __attribute__((ext_vector_type(8))) short bf16x8;
typedef __attribute__((ext_vector_type(8))) unsigned short u16x8;
typedef __attribute__((ext_vector_type(4))) unsigned short u16x4;
typedef __attribute__((ext_vector_type(4))) float f32x4;

#define MFMA16 __builtin_amdgcn_mfma_f32_16x16x32_bf16

#define GLDS(gp, lp) __builtin_amdgcn_global_load_lds( \
    (const __attribute__((address_space(1))) unsigned int*)(gp), \
    (__attribute__((address_space(3))) unsigned int*)(lp), 16, 0, 0)

__device__ __forceinline__ unsigned short f2bf(float f) {
    union { float f; unsigned int u; } v; v.f = f;
    unsigned int r = v.u + 0x7fffu + ((v.u >> 16) & 1u);
    return (unsigned short)(r >> 16);
}

// bx<4096: fp32->bf16 x-convert (+mask->bf16 in first 32 blocks).
// bx>=4096: weight transposes (w_qkv 1024x3072, w_out 1024x1024).
__global__ void k_prep(const float* __restrict__ x, unsigned short* __restrict__ xb,
                       const int* __restrict__ mask, unsigned short* __restrict__ mb,
                       const float* __restrict__ wqkv, unsigned short* __restrict__ w1t,
                       const float* __restrict__ wout, unsigned short* __restrict__ w2t) {
    __shared__ float tile[32][33];
    const int bx = blockIdx.x;
    if (bx < 4096) {
        size_t i = ((size_t)bx * 256 + threadIdx.x) * 8;
        float4 f0 = *(const float4*)(x + i);
        float4 f1 = *(const float4*)(x + i + 4);
        u16x8 v;
        v[0] = f2bf(f0.x); v[1] = f2bf(f0.y); v[2] = f2bf(f0.z); v[3] = f2bf(f0.w);
        v[4] = f2bf(f1.x); v[5] = f2bf(f1.y); v[6] = f2bf(f1.z); v[7] = f2bf(f1.w);
        *(u16x8*)(xb + i) = v;
        if (bx < 32) {
            int j = bx * 256 + threadIdx.x;
            mb[j] = mask[j] ? (unsigned short)0x3F80 : (unsigned short)0;
        }
    } else {
        const int b2 = bx - 4096;
        const int cb = b2 & 127, rb = b2 >> 7;
        const float* in = (cb < 96) ? wqkv : wout;
        unsigned short* out = (cb < 96) ? w1t : w2t;
        const int C = (cb < 96) ? 3072 : 1024;
        const int c0 = ((cb < 96) ? cb : cb - 96) * 32;
        const int r0 = rb * 32;
        int tx = threadIdx.x & 31, ty = threadIdx.x >> 5;
        for (int i = ty; i < 32; i += 8)
            tile[i][tx] = in[(size_t)(r0 + i) * C + (c0 + tx)];
        __syncthreads();
        for (int i = ty; i < 32; i += 8)
            out[(size_t)(c0 + i) * 1024 + (r0 + tx)] = f2bf(tile[tx][i]);
    }
}

// C[M][N] = A[M][K] * Bt[N][K]^T.  128x128 tile, BK=64, swizzled LDS (v8/v12, unchanged).
template <int MODE>
__global__ __launch_bounds__(256) void k_gemm_bt(
    const unsigned short* __restrict__ Ab,
    const unsigned short* __restrict__ Bt,
    float* __restrict__ Cf,
    unsigned short* __restrict__ qb,
    unsigned short* __restrict__ kb,
    unsigned short* __restrict__ vt,
    const int* __restrict__ mask,
    int N, int K)
{
    __shared__ __align__(16) unsigned short la[128 * 64];
    __shared__ __align__(16) unsigned short lb[128 * 64];
    const int t = threadIdx.x;
    const int m0 = blockIdx.y * 128, n0 = blockIdx.x * 128;
    const int w = t >> 6, lane = t & 63;
    const int wm = (w & 1) * 64, wn = (w >> 1) * 64;
    const int lr = lane & 15, lq = lane >> 4;
    const int lr7 = lr & 7;
    const int rowb = lane >> 3;
    const int g8 = (((lane & 7) - rowb) & 7) * 8;

    f32x4 acc[4][4];
    for (int i = 0; i < 4; ++i)
        for (int j = 0; j < 4; ++j)
            acc[i][j] = (f32x4){0.f, 0.f, 0.f, 0.f};

    for (int k0 = 0; k0 < K; k0 += 64) {
        #pragma unroll
        for (int r = 0; r < 4; ++r) {
            const int rg = w * 8 + r * 32;
            GLDS(&Ab[(size_t)(m0 + rg + rowb) * K + k0 + g8], &la[rg * 64]);
            GLDS(&Bt[(size_t)(n0 + rg + rowb) * K + k0 + g8], &lb[rg * 64]);
        }
        __syncthreads();
        #pragma unroll
        for (int ks = 0; ks < 2; ++ks) {
            const int pa = ((ks * 4 + lq + lr7) & 7) * 8;
            bf16x8 af[4], bg[4];
            #pragma unroll
            for (int i = 0; i < 4; ++i) {
                af[i] = *(const bf16x8*)&la[(wm + i * 16 + lr) * 64 + pa];
                bg[i] = *(const bf16x8*)&lb[(wn + i * 16 + lr) * 64 + pa];
            }
            #pragma unroll
            for (int i = 0; i < 4; ++i)
                #pragma unroll
                for (int j = 0; j < 4; ++j)
                    acc[i][j] = MFMA16(af[i], bg[j], acc[i][j], 0, 0, 0);
        }
        __syncthreads();
    }

    const float QSCALE = 0.18033688f;  // log2(e)/8, folded into Q
    if (MODE == 0) {
        for (int i = 0; i < 4; ++i)
            for (int j = 0; j < 4; ++j)
                for (int r = 0; r < 4; ++r) {
                    int row = m0 + wm + i * 16 + lq * 4 + r;
                    int col = n0 + wn + j * 16 + lr;
                    Cf[(size_t)row * N + col] = acc[i][j][r];
                }
    } else {
        const int which = n0 >> 10;
        if (which < 2) {
            unsigned short* dst = which ? kb : qb;
            const float sc = which ? 1.0f : QSCALE;
            for (int i = 0; i < 4; ++i)
                for (int j = 0; j < 4; ++j)
                    for (int r = 0; r < 4; ++r) {
                        int row = m0 + wm + i * 16 + lq * 4 + r;
                        int col = n0 + wn + j * 16 + lr;
                        int h = (col >> 6) & 15, d = col & 63;
                        int b = row >> 11, s = row & 2047;
                        dst[((size_t)(b * 16 + h) * 2048 + s) * 64 + d] = f2bf(acc[i][j][r] * sc);
                    }
        } else {
            for (int i = 0; i < 4; ++i) {
                int s0 = m0 + wm + i * 16 + lq * 4;
                int b = s0 >> 11, s = s0 & 2047;
                int4 m4 = *(const int4*)&mask[b * 2048 + s];
                for (int j = 0; j < 4; ++j) {
                    int col = n0 + wn + j * 16 + lr;
                    int h = (col >> 6) & 15, d = col & 63;
                    u16x4 pv;
                    pv[0] = m4.x ? f2bf(acc[i][j][0]) : (unsigned short)0;
                    pv[1] = m4.y ? f2bf(acc[i][j][1]) : (unsigned short)0;
                    pv[2] = m4.z ? f2bf(acc[i][j][2]) : (unsigned short)0;
                    pv[3] = m4.w ? f2bf(acc[i][j][3]) : (unsigned short)0;
                    *(u16x4*)&vt[((size_t)(b * 16 + h) * 64 + d) * 2048 + s] = pv;
                }
            }
        }
    }
}

// Flash attention v17. grid = (64 bh, 16 stripes); block 512 = 8 waves x 16 q.
// ONE stripe per block, stripe = 15 - blockIdx.y => big stripes dispatch
// first (LPT packing); 1024 blocks -> 3 blocks/CU (LDS 48KB) vs v16's 2.
// XCD = linear%8 = bh%8 -> per-head K/V pinned to one XCD's L2.
// P row = 64 shorts; 16B-unit c stored at (c ^ (lr&7)) -> uniform banks.
__global__ __launch_bounds__(512, 6) void k_attn(
    const unsigned short* __restrict__ qb,
    const unsigned short* __restrict__ kb,
    const unsigned short* __restrict__ vt,
    const unsigned short* __restrict__ maskbg,
    unsigned short* __restrict__ ao)
{
    __shared__ __align__(16) unsigned short kt_lds[2][64 * 64];  // [key][d], d-blocks XOR key&7
    __shared__ __align__(16) unsigned short vt_lds[2][64 * 64];  // [d][key], key-blocks XOR d&7
    __shared__ __align__(16) unsigned short plds[8][16 * 64];    // P[q][key] per wave, slot-swizzled

    const int t = threadIdx.x;
    const int w = t >> 6, lane = t & 63;
    const int lr = lane & 15, lq = lane >> 4;
    const int lr7 = lr & 7;
    const int bh = blockIdx.x, b = bh >> 4, h = bh & 15;

    const unsigned short* qp = qb + (size_t)bh * 2048 * 64;
    const unsigned short* kp = kb + (size_t)bh * 2048 * 64;
    const unsigned short* vp = vt + (size_t)bh * 64 * 2048;
    const unsigned short* mbg = maskbg + b * 2048;
    unsigned short* pw = plds[w];

    const int rowb = lane >> 3, c8 = lane & 7;
    const int sc8 = (c8 ^ rowb) * 8;                 // XOR-swizzled source column block

    auto stage = [&](int c) {
        const int buf = c & 1;
        const int k0 = c * 64;
        const int rg = 8 * w;
        const int row = rg + rowb;
        GLDS(&kp[(size_t)(k0 + row) * 64 + sc8], &kt_lds[buf][rg * 64]);
        GLDS(&vp[(size_t)row * 2048 + k0 + sc8], &vt_lds[buf][rg * 64]);
    };

    const int stripe = 15 - (int)blockIdx.y;   // big stripes dispatch first
    const int q0w = stripe * 128 + w * 16;

    bf16x8 aq0 = *(const bf16x8*)&qp[(q0w + lr) * 64 + lq * 8];
    bf16x8 aq1 = *(const bf16x8*)&qp[(q0w + lr) * 64 + 32 + lq * 8];

    f32x4 acc[4], lacc;
    lacc = (f32x4){0.f, 0.f, 0.f, 0.f};
    #pragma unroll
    for (int j = 0; j < 4; ++j) acc[j] = (f32x4){0.f, 0.f, 0.f, 0.f};

    const int nch = 2 * (stripe + 1);
    stage(0);
    for (int c = 0; c < nch; ++c) {
        __syncthreads();
        if (c + 1 < nch) stage(c + 1);
        const int k0 = c * 64;
        if (k0 < q0w + 16) {
            const unsigned short* kt = kt_lds[c & 1];
            const unsigned short* vtl = vt_lds[c & 1];
            const bool causal = (k0 + 63 > q0w);
            const int kcol0 = (lq ^ lr7) * 8;
            const int kcol1 = ((4 + lq) ^ lr7) * 8;
            #pragma unroll
            for (int ki = 0; ki < 4; ++ki) {
                bf16x8 kf0 = *(const bf16x8*)&kt[(ki * 16 + lr) * 64 + kcol0];
                bf16x8 kf1 = *(const bf16x8*)&kt[(ki * 16 + lr) * 64 + kcol1];
                f32x4 s = (f32x4){0.f, 0.f, 0.f, 0.f};
                s = MFMA16(kf0, aq0, s, 0, 0, 0);
                s = MFMA16(kf1, aq1, s, 0, 0, 0);
                unsigned int u[4];
                #pragma unroll
                for (int r = 0; r < 4; ++r) {
                    float scv = s[r];
                    if (causal) {
                        int key = k0 + ki * 16 + lq * 4 + r;
                        int qq  = q0w + lr;
                        scv = (key <= qq) ? scv : -3.0e38f;
                    }
                    float p = __builtin_amdgcn_exp2f(scv);
                    union { float f; unsigned int u; } cv; cv.f = p;
                    u[r] = cv.u;
                }
                uint2 pk;
                pk.x = __builtin_amdgcn_perm(u[1], u[0], 0x07060302u);
                pk.y = __builtin_amdgcn_perm(u[3], u[2], 0x07060302u);
                // P slot-swizzle: 16B-unit c = ki*2+(lq>>1), half = lq&1,
                // stored at unit (c ^ lr7)  -> write banks uniform (4-phase min)
                *(uint2*)&pw[lr * 64 + (((ki * 2 + (lq >> 1)) ^ lr7) * 8) + (lq & 1) * 4] = pk;
            }
            #pragma unroll
            for (int kc = 0; kc < 64; kc += 32) {
                // read 16B-unit c = kc/8 + lq at swizzled slot (c ^ lr7)
                bf16x8 pf = *(const bf16x8*)&pw[lr * 64 + ((((kc >> 3) + lq) ^ lr7) * 8)];
                bf16x8 mb = *(const bf16x8*)&mbg[k0 + kc + lq * 8];
                const int vcol = (((kc >> 3) + lq) ^ lr7) * 8;
                #pragma unroll
                for (int j = 0; j < 4; ++j) {
                    bf16x8 vf = *(const bf16x8*)&vtl[(j * 16 + lr) * 64 + vcol];
                    acc[j] = MFMA16(pf, vf, acc[j], 0, 0, 0);
                }
                lacc = MFMA16(pf, mb, lacc, 0, 0, 0);
            }
        }
    }

    #pragma unroll
    for (int r = 0; r < 4; ++r) {
        float inv = 1.0f / fmaxf(lacc[r], 1e-30f);
        int row = q0w + lq * 4 + r;
        #pragma unroll
        for (int j = 0; j < 4; ++j) {
            int d = j * 16 + lr;
            ao[(size_t)(b * 2048 + row) * 1024 + h * 64 + d] = f2bf(acc[j][r] * inv);
        }
    }
}

extern "C" void kernel_launch(void* const* d_in, const int* in_sizes, int n_in,
                              void* d_out, int out_size, void* d_ws, size_t ws_size,
                              hipStream_t stream)
{
    const float* x    = (const float*)d_in[0];
    const int*   mask = (const int*)d_in[1];
    const float* wqkv = (const float*)d_in[2];
    const float* wout = (const float*)d_in[3];
    float* out = (float*)d_out;

    const size_t NEED = ((size_t)8192 * 1024 + (size_t)3072 * 1024 + (size_t)1024 * 1024 +
                         3 * (size_t)64 * 2048 * 64 + (size_t)8192 * 1024 + 8192) * 2;
    if (ws_size < NEED) return;

    char* ws = (char*)d_ws;
    unsigned short* xb  = (unsigned short*)ws; ws += (size_t)8192 * 1024 * 2;
    unsigned short* w1t = (unsigned short*)ws; ws += (size_t)3072 * 1024 * 2;
    unsigned short* w2t = (unsigned short*)ws; ws += (size_t)1024 * 1024 * 2;
    unsigned short* qb  = (unsigned short*)ws; ws += (size_t)64 * 2048 * 64 * 2;
    unsigned short* kb  = (unsigned short*)ws; ws += (size_t)64 * 2048 * 64 * 2;
    unsigned short* vt  = (unsigned short*)ws; ws += (size_t)64 * 64 * 2048 * 2;
    unsigned short* ao  = (unsigned short*)ws; ws += (size_t)8192 * 1024 * 2;
    unsigned short* mbg = (unsigned short*)ws; ws += (size_t)8192 * 2;

    k_prep<<<dim3(8192), 256, 0, stream>>>(x, xb, mask, mbg, wqkv, w1t, wout, w2t);
    k_gemm_bt<1><<<dim3(24, 64), 256, 0, stream>>>(xb, w1t, nullptr, qb, kb, vt, mask, 3072, 1024);
    k_attn<<<dim3(64, 16), 512, 0, stream>>>(qb, kb, vt, mbg, ao);
    k_gemm_bt<0><<<dim3(8, 64), 256, 0, stream>>>(ao, w2t, out, nullptr, nullptr, nullptr, nullptr, 1024, 1024);
}